// Round 13
// baseline (4428.554 us; speedup 1.0000x reference)
//
#include <hip/hip_runtime.h>
#include <hip/hip_bf16.h>
#include <cstdint>
#include <cstddef>

typedef __bf16 bf16x8 __attribute__((ext_vector_type(8)));
typedef float f32x4 __attribute__((ext_vector_type(4)));
typedef unsigned short u16x4 __attribute__((ext_vector_type(4)));
typedef unsigned short u16x8 __attribute__((ext_vector_type(8)));

namespace {
constexpr int kT = 8192;        // tokens
constexpr int kH = 1024;
constexpr int kE = 8;
constexpr int kI = 2752;
constexpr int kIP = 2816;       // I padded to 22*128
constexpr int kPairCap = 25728; // 201*128 >= 16384 + 8*127 + 8192

constexpr size_t SZ_XB  = (size_t)kT * kH * 2;
constexpr size_t SZ_WB  = (size_t)kE * kIP * kH * 2;
constexpr size_t SZ_SB  = (size_t)kIP * kH * 2;
constexpr size_t SZ_HDN = (size_t)kPairCap * kIP * 2;

constexpr size_t OFF_XB  = 0;
constexpr size_t OFF_WGB = OFF_XB + SZ_XB;
constexpr size_t OFF_WUB = OFF_WGB + SZ_WB;
constexpr size_t OFF_SGB = OFF_WUB + SZ_WB;
constexpr size_t OFF_SUB = OFF_SGB + SZ_SB;
constexpr size_t OFF_WDB = OFF_SUB + SZ_SB;           // = 120,586,240
constexpr size_t OFF_SDB = OFF_WDB + SZ_WB;
constexpr size_t OFF_HDN = OFF_SDB + SZ_SB;
constexpr size_t OFF_PT  = OFF_HDN + SZ_HDN;
constexpr size_t OFF_PW  = OFF_PT + (size_t)kPairCap * 4;
constexpr size_t OFF_SLT = OFF_PW + (size_t)kPairCap * 4;
constexpr size_t OFF_CNT = OFF_SLT + (size_t)kT * 2 * 4;
constexpr size_t OFF_CUR = OFF_CNT + 256;
constexpr size_t OFF_SEG = OFF_CUR + 256;
constexpr size_t WS_NEED = OFF_SEG + 256;
constexpr size_t OFF_P   = 0;   // P bf16 overlays dead X/Wg/Wu region
constexpr size_t OFF_TI  = OFF_HDN;
constexpr size_t OFF_TW  = OFF_HDN + (size_t)kT * 2 * 4;
static_assert((size_t)kPairCap * kH * 2 <= OFF_WDB, "P overlay fits");
}

__device__ __forceinline__ unsigned short f2bf(float f) {
  unsigned u = __builtin_bit_cast(unsigned, f);
  u += 0x7fffu + ((u >> 16) & 1u);
  return (unsigned short)(u >> 16);
}
__device__ __forceinline__ float bf2f(unsigned short v) {
  return __builtin_bit_cast(float, (unsigned)v << 16);
}

typedef __attribute__((address_space(1))) const unsigned int gu32;
typedef __attribute__((address_space(3))) unsigned int lu32;
__device__ __forceinline__ void gload16(const unsigned short* g, unsigned short* l) {
  __builtin_amdgcn_global_load_lds((gu32*)g, (lu32*)l, 16, 0, 0);
}

// ---------- fp32 -> bf16 converts (with I-padding) ----------
__global__ __launch_bounds__(256) void k_conv_x(const float* __restrict__ src,
                                                unsigned short* __restrict__ dst) {
  int i = blockIdx.x * 256 + threadIdx.x;
  f32x4 v = reinterpret_cast<const f32x4*>(src)[i];
  u16x4 o;
  #pragma unroll
  for (int j = 0; j < 4; ++j) o[j] = f2bf(v[j]);
  reinterpret_cast<u16x4*>(dst)[i] = o;
}

__global__ __launch_bounds__(256) void k_conv_gateup(const float* __restrict__ src,
                                                     unsigned short* __restrict__ dst,
                                                     int Eo) {
  int i = blockIdx.x * 256 + threadIdx.x;
  int c4 = i & 255;
  int r  = (i >> 8) % kIP;
  int e  = i / (256 * kIP);
  u16x4 o = (u16x4)0;
  if (r < kI) {
    f32x4 v = __builtin_nontemporal_load(
        reinterpret_cast<const f32x4*>(src) + ((size_t)e * kI + r) * 256 + c4);
    #pragma unroll
    for (int j = 0; j < 4; ++j) o[j] = f2bf(v[j]);
  }
  reinterpret_cast<u16x4*>(dst)[i] = o;
}

__global__ __launch_bounds__(256) void k_conv_down(const float* __restrict__ src,
                                                   unsigned short* __restrict__ dst,
                                                   int Eo) {
  int i = blockIdx.x * 256 + threadIdx.x;
  int c4 = i % 704;
  int rr = i / 704;
  int r  = rr % kH;
  int e  = rr / kH;
  u16x4 o = (u16x4)0;
  if (c4 < 688) {
    f32x4 v = __builtin_nontemporal_load(
        reinterpret_cast<const f32x4*>(src) + ((size_t)e * kH + r) * 688 + c4);
    #pragma unroll
    for (int j = 0; j < 4; ++j) o[j] = f2bf(v[j]);
  }
  reinterpret_cast<u16x4*>(dst)[i] = o;
}

// ---------- gate: softmax over 8 logits, top-2, renorm ----------
__global__ __launch_bounds__(256) void k_gate(const float* __restrict__ x,
                                              const float* __restrict__ gw,
                                              int* __restrict__ tki,
                                              float* __restrict__ tkw,
                                              int* __restrict__ cnt) {
  const int l = threadIdx.x & 63;
  const int t = blockIdx.x * 4 + (threadIdx.x >> 6);
  const float* xr = x + (size_t)t * kH + l * 16;
  float xv[16];
  #pragma unroll
  for (int j = 0; j < 16; j += 4) {
    f32x4 v = *reinterpret_cast<const f32x4*>(xr + j);
    xv[j] = v[0]; xv[j+1] = v[1]; xv[j+2] = v[2]; xv[j+3] = v[3];
  }
  float acc[kE];
  #pragma unroll
  for (int e = 0; e < kE; ++e) {
    const float* gr = gw + e * kH + l * 16;
    float s = 0.f;
    #pragma unroll
    for (int j = 0; j < 16; j += 4) {
      f32x4 g = *reinterpret_cast<const f32x4*>(gr + j);
      s += xv[j]*g[0] + xv[j+1]*g[1] + xv[j+2]*g[2] + xv[j+3]*g[3];
    }
    acc[e] = s;
  }
  #pragma unroll
  for (int e = 0; e < kE; ++e) {
    #pragma unroll
    for (int off = 32; off > 0; off >>= 1) acc[e] += __shfl_xor(acc[e], off, 64);
  }
  if (l == 0) {
    float m = acc[0];
    #pragma unroll
    for (int e = 1; e < kE; ++e) m = fmaxf(m, acc[e]);
    float p[kE]; float sum = 0.f;
    #pragma unroll
    for (int e = 0; e < kE; ++e) { p[e] = __expf(acc[e] - m); sum += p[e]; }
    float inv = 1.f / sum;
    int i1 = 0; float v1 = -1.f;
    #pragma unroll
    for (int e = 0; e < kE; ++e) { float s = p[e] * inv; if (s > v1) { v1 = s; i1 = e; } }
    int i2 = -1; float v2 = -1.f;
    #pragma unroll
    for (int e = 0; e < kE; ++e) {
      if (e == i1) continue;
      float s = p[e] * inv; if (s > v2) { v2 = s; i2 = e; }
    }
    float denom = v1 + v2 + 1e-20f;
    tki[t*2]   = i1; tki[t*2+1] = i2;
    tkw[t*2]   = v1 / denom; tkw[t*2+1] = v2 / denom;
    atomicAdd(&cnt[i1], 1); atomicAdd(&cnt[i2], 1);
  }
}

// ---------- segment offsets (padded to 128) ----------
__global__ void k_seg(const int* __restrict__ cnt, int* __restrict__ seg,
                      int* __restrict__ cur) {
  int off = 0;
  for (int e = 0; e < kE; ++e) {
    seg[e] = off; cur[e] = off;
    off += (cnt[e] + 127) & ~127;
  }
  seg[8] = off;
  seg[9] = off + kT;
}

// ---------- fill pair lists + slot map ----------
__global__ __launch_bounds__(256) void k_fill(const int* __restrict__ tki,
                                              const float* __restrict__ tkw,
                                              const int* __restrict__ seg,
                                              int* __restrict__ cur,
                                              int* __restrict__ pt,
                                              float* __restrict__ pw,
                                              int* __restrict__ slt) {
  int i = blockIdx.x * 256 + threadIdx.x;
  if (i < kT * 2) {
    int e = tki[i];
    int pos = atomicAdd(&cur[e], 1);
    pt[pos] = i >> 1;
    pw[pos] = tkw[i];
    slt[i] = pos;
  } else {
    int t = i - kT * 2;          // shared-expert segment, weight 1
    int pos = seg[8] + t;
    pt[pos] = t;
    pw[pos] = 1.0f;
  }
}

// ===================================================================
// Ring-2 counted-vmcnt pipeline, 24 KB slots (48 KB LDS, 3 blocks/CU).
// Loop order (ring-2-legal): VMSYNC(6) -> COMP(slot) -> barrier ->
// STAGE next chunk into the just-freed slot. Steady wait = 6 (one chunk
// in flight); tail 6 then 0. The 3rd co-resident block absorbs the
// residual barrier stall the counted ring can't hide.
// ===================================================================

#define VMSYNC(N)                                                     \
  { asm volatile("s_waitcnt vmcnt(" #N ")" ::: "memory");             \
    __builtin_amdgcn_s_barrier();                                     \
    __builtin_amdgcn_sched_barrier(0); }

// ---------- pass A: hdn = silu(X Wg^T) * (X Wu^T) ----------
// Block 128 pairs x 128 I-cols dual, wave 64x64 dual.
// Slot 24KB: A[128x32]@0, G[128x32]@8192B, U[128x32]@16384B.
__global__ __launch_bounds__(256, 3) void k_gu(
    const unsigned short* __restrict__ xb,
    const unsigned short* __restrict__ Wgb,
    const unsigned short* __restrict__ Wub,
    const unsigned short* __restrict__ Sgb,
    const unsigned short* __restrict__ Sub,
    const int* __restrict__ pt,
    const int* __restrict__ seg,
    unsigned short* __restrict__ hdn) {
  __shared__ alignas(16) unsigned short lds[24576];  // 48 KB = 2 x 24KB slots
  const int tid = threadIdx.x;
  const int bn = blockIdx.x, bm = blockIdx.y;
  const int row0 = bm * 128, n0 = bn * 128;
  if (row0 >= seg[9]) return;
  int e = 0;
  while (e < 8 && row0 >= seg[e+1]) ++e;
  const unsigned short* Bg = (e < 8) ? Wgb + (size_t)e * kIP * kH : Sgb;
  const unsigned short* Bu = (e < 8) ? Wub + (size_t)e * kIP * kH : Sub;

  const int ur  = tid >> 2;
  const int csw = ((tid & 3) ^ ((tid >> 3) & 3)) * 8;   // swizzled elem offset
  const unsigned short* sA0 = xb + (size_t)pt[row0 + ur]      * kH + csw;
  const unsigned short* sA1 = xb + (size_t)pt[row0 + 64 + ur] * kH + csw;
  const unsigned short* sG0 = Bg + (size_t)(n0 + ur) * kH + csw;
  const unsigned short* sG1 = Bg + (size_t)(n0 + 64 + ur) * kH + csw;
  const unsigned short* sU0 = Bu + (size_t)(n0 + ur) * kH + csw;
  const unsigned short* sU1 = Bu + (size_t)(n0 + 64 + ur) * kH + csw;

  const int w = tid >> 6, l = tid & 63;
  const int wm = (w >> 1) * 64, wn = (w & 1) * 64;
  const int lr = l & 15, lk = l >> 4;
  unsigned short* const dst0 = &lds[w * 512];   // wave-uniform stage base

  int offA[4], offG[4];
  #pragma unroll
  for (int fm = 0; fm < 4; ++fm) {
    int r = wm + fm * 16 + lr;
    offA[fm] = (r * 4 + (lk ^ ((r >> 1) & 3))) * 16;
  }
  #pragma unroll
  for (int fn = 0; fn < 4; ++fn) {
    int rn = wn + fn * 16 + lr;
    offG[fn] = 8192 + (rn * 4 + (lk ^ ((rn >> 1) & 3))) * 16;
  }
  f32x4 ag[4][4] = {}, au[4][4] = {};

#define GU_STAGE(S)                                                   \
  { unsigned short* b = dst0 + (S) * 12288;                           \
    gload16(sA0, b);         gload16(sA1, b + 2048);                  \
    gload16(sG0, b + 4096);  gload16(sG1, b + 6144);                  \
    gload16(sU0, b + 8192);  gload16(sU1, b + 10240);                 \
    sA0 += 32; sA1 += 32; sG0 += 32; sG1 += 32; sU0 += 32; sU1 += 32; }

#define GU_COMP(S)                                                    \
  { const char* base = (const char*)lds + (S) * 24576;                \
    bf16x8 af[4], gf[4], uf[4];                                       \
    _Pragma("unroll")                                                 \
    for (int fm = 0; fm < 4; ++fm)                                    \
      af[fm] = *(const bf16x8*)(base + offA[fm]);                     \
    _Pragma("unroll")                                                 \
    for (int fn = 0; fn < 4; ++fn) {                                  \
      gf[fn] = *(const bf16x8*)(base + offG[fn]);                     \
      uf[fn] = *(const bf16x8*)(base + offG[fn] + 8192);              \
    }                                                                 \
    __builtin_amdgcn_s_setprio(1);                                    \
    _Pragma("unroll")                                                 \
    for (int fm = 0; fm < 4; ++fm) {                                  \
      _Pragma("unroll")                                               \
      for (int fn = 0; fn < 4; ++fn) {                                \
        ag[fm][fn] = __builtin_amdgcn_mfma_f32_16x16x32_bf16(af[fm], gf[fn], ag[fm][fn], 0, 0, 0); \
        au[fm][fn] = __builtin_amdgcn_mfma_f32_16x16x32_bf16(af[fm], uf[fn], au[fm][fn], 0, 0, 0); \
      }                                                               \
    }                                                                 \
    __builtin_amdgcn_s_setprio(0); }

  GU_STAGE(0); GU_STAGE(1);
  for (int h = 0; h < 30; ++h) {              // chunks 0..29; NH = 32
    VMSYNC(6);                                // chunk h ready; h+1 in flight
    GU_COMP(h & 1);
    __builtin_amdgcn_s_barrier();             // slot (h&1) fully consumed
    GU_STAGE(h & 1);                          // chunk h+2 into freed slot
  }
  VMSYNC(6); GU_COMP(0);                      // chunk 30
  __builtin_amdgcn_s_barrier();
  VMSYNC(0); GU_COMP(1);                      // chunk 31
#undef GU_STAGE
#undef GU_COMP

  #pragma unroll
  for (int fm = 0; fm < 4; ++fm) {
    #pragma unroll
    for (int fn = 0; fn < 4; ++fn) {
      #pragma unroll
      for (int j = 0; j < 4; ++j) {
        int r = wm + fm * 16 + lk * 4 + j;
        int c = wn + fn * 16 + lr;
        float g = ag[fm][fn][j], u = au[fm][fn][j];
        float h = g / (1.f + __expf(-g)) * u;
        hdn[(size_t)(row0 + r) * kIP + (n0 + c)] = f2bf(h);
      }
    }
  }
}

// ---------- pass B: P[pair,:] = pw[pair] * (hdn[pair,:] @ Wd^T) ----------
// Block 128x256, wave 64x128. Slot 24KB: A[128x32]@0, B[256x32]@8192B.
__global__ __launch_bounds__(256, 3) void k_down(
    const unsigned short* __restrict__ hdn,
    const unsigned short* __restrict__ Wdb,
    const unsigned short* __restrict__ Sdb,
    const float* __restrict__ pw,
    const int* __restrict__ seg,
    unsigned short* __restrict__ P) {
  __shared__ alignas(16) unsigned short lds[24576];  // 48 KB
  const int tid = threadIdx.x;
  const int bn = blockIdx.x, bm = blockIdx.y;
  const int row0 = bm * 128, n0 = bn * 256;
  if (row0 >= seg[9]) return;
  int e = 0;
  while (e < 8 && row0 >= seg[e+1]) ++e;
  const unsigned short* Bd = (e < 8) ? Wdb + (size_t)e * kH * kIP : Sdb;

  const int ur  = tid >> 2;
  const int csw = ((tid & 3) ^ ((tid >> 3) & 3)) * 8;
  const unsigned short* sA0 = hdn + (size_t)(row0 + ur)      * kIP + csw;
  const unsigned short* sA1 = hdn + (size_t)(row0 + 64 + ur) * kIP + csw;
  const unsigned short* sB0 = Bd  + (size_t)(n0 + ur)        * kIP + csw;
  const unsigned short* sB1 = Bd  + (size_t)(n0 + 64 + ur)   * kIP + csw;
  const unsigned short* sB2 = Bd  + (size_t)(n0 + 128 + ur)  * kIP + csw;
  const unsigned short* sB3 = Bd  + (size_t)(n0 + 192 + ur)  * kIP + csw;

  const int w = tid >> 6, l = tid & 63;
  const int wm = (w >> 1) * 64, wn = (w & 1) * 128;
  const int lr = l & 15, lk = l >> 4;
  unsigned short* const dst0 = &lds[w * 512];

  int offA[4], offB[8];
  #pragma unroll
  for (int fm = 0; fm < 4; ++fm) {
    int r = wm + fm * 16 + lr;
    offA[fm] = (r * 4 + (lk ^ ((r >> 1) & 3))) * 16;
  }
  #pragma unroll
  for (int fn = 0; fn < 8; ++fn) {
    int rn = wn + fn * 16 + lr;
    offB[fn] = 8192 + (rn * 4 + (lk ^ ((rn >> 1) & 3))) * 16;
  }
  f32x4 acc[4][8] = {};

#define DN_STAGE(S)                                                   \
  { unsigned short* b = dst0 + (S) * 12288;                           \
    gload16(sA0, b);         gload16(sA1, b + 2048);                  \
    gload16(sB0, b + 4096);  gload16(sB1, b + 6144);                  \
    gload16(sB2, b + 8192);  gload16(sB3, b + 10240);                 \
    sA0 += 32; sA1 += 32; sB0 += 32; sB1 += 32; sB2 += 32; sB3 += 32; }

#define DN_COMP(S)                                                    \
  { const char* base = (const char*)lds + (S) * 24576;                \
    bf16x8 af[4], bfr[8];                                             \
    _Pragma("unroll")                                                 \
    for (int fm = 0; fm < 4; ++fm)                                    \
      af[fm] = *(const bf16x8*)(base + offA[fm]);                     \
    _Pragma("unroll")                                                 \
    for (int fn = 0; fn < 8; ++fn)                                    \
      bfr[fn] = *(const bf16x8*)(base + offB[fn]);                    \
    __builtin_amdgcn_s_setprio(1);                                    \
    _Pragma("unroll")                                                 \
    for (int fm = 0; fm < 4; ++fm) {                                  \
      _Pragma("unroll")                                               \
      for (int fn = 0; fn < 8; ++fn)                                  \
        acc[fm][fn] = __builtin_amdgcn_mfma_f32_16x16x32_bf16(af[fm], bfr[fn], acc[fm][fn], 0, 0, 0); \
    }                                                                 \
    __builtin_amdgcn_s_setprio(0); }

  DN_STAGE(0); DN_STAGE(1);
  for (int h = 0; h < 86; ++h) {              // chunks 0..85; NH = 88
    VMSYNC(6);
    DN_COMP(h & 1);
    __builtin_amdgcn_s_barrier();
    DN_STAGE(h & 1);
  }
  VMSYNC(6); DN_COMP(0);                      // chunk 86
  __builtin_amdgcn_s_barrier();
  VMSYNC(0); DN_COMP(1);                      // chunk 87
#undef DN_STAGE
#undef DN_COMP

  #pragma unroll
  for (int fm = 0; fm < 4; ++fm) {
    #pragma unroll
    for (int j = 0; j < 4; ++j) {
      int r = row0 + wm + fm * 16 + lk * 4 + j;
      float wt = pw[r];
      unsigned short* prow = P + (size_t)r * kH + n0;
      #pragma unroll
      for (int fn = 0; fn < 8; ++fn)
        prow[wn + fn * 16 + lr] = f2bf(acc[fm][fn][j] * wt);
    }
  }
}

// ---------- final: y[t] = P[s1] + P[s2] + P[shared] (P in bf16) ----------
__global__ __launch_bounds__(256) void k_reduce(const unsigned short* __restrict__ P,
                                                const int* __restrict__ slt,
                                                const int* __restrict__ seg,
                                                float* __restrict__ out) {
  const int t = blockIdx.x, c = threadIdx.x;
  const int s1 = slt[t * 2], s2 = slt[t * 2 + 1], sh = seg[8] + t;
  u16x4 a = reinterpret_cast<const u16x4*>(P + (size_t)s1 * kH)[c];
  u16x4 b = reinterpret_cast<const u16x4*>(P + (size_t)s2 * kH)[c];
  u16x4 d = reinterpret_cast<const u16x4*>(P + (size_t)sh * kH)[c];
  f32x4 o;
  #pragma unroll
  for (int j = 0; j < 4; ++j) o[j] = bf2f(a[j]) + bf2f(b[j]) + bf2f(d[j]);
  reinterpret_cast<f32x4*>(out + (size_t)t * kH)[c] = o;
}

extern "C" void kernel_launch(void* const* d_in, const int* in_sizes, int n_in,
                              void* d_out, int out_size, void* d_ws, size_t ws_size,
                              hipStream_t stream) {
  const float* x  = (const float*)d_in[0];
  const float* gw = (const float*)d_in[1];
  const float* Wg = (const float*)d_in[2];
  const float* Wu = (const float*)d_in[3];
  const float* Wd = (const float*)d_in[4];
  const float* Sg = (const float*)d_in[5];
  const float* Su = (const float*)d_in[6];
  const float* Sd = (const float*)d_in[7];
  float* out = (float*)d_out;
  char* ws = (char*)d_ws;
  if (ws_size < WS_NEED) return;

  unsigned short* xb  = (unsigned short*)(ws + OFF_XB);
  unsigned short* Wgb = (unsigned short*)(ws + OFF_WGB);
  unsigned short* Wub = (unsigned short*)(ws + OFF_WUB);
  unsigned short* Sgb = (unsigned short*)(ws + OFF_SGB);
  unsigned short* Sub = (unsigned short*)(ws + OFF_SUB);
  unsigned short* Wdb = (unsigned short*)(ws + OFF_WDB);
  unsigned short* Sdb = (unsigned short*)(ws + OFF_SDB);
  unsigned short* hdn = (unsigned short*)(ws + OFF_HDN);
  unsigned short* P  = (unsigned short*)(ws + OFF_P);
  int*   pt  = (int*)(ws + OFF_PT);
  float* pw  = (float*)(ws + OFF_PW);
  int*   slt = (int*)(ws + OFF_SLT);
  int*   cnt = (int*)(ws + OFF_CNT);
  int*   cur = (int*)(ws + OFF_CUR);
  int*   seg = (int*)(ws + OFF_SEG);
  int*   tki = (int*)(ws + OFF_TI);
  float* tkw = (float*)(ws + OFF_TW);

  hipMemsetAsync(ws + OFF_PT, 0, OFF_SEG - OFF_PT, stream);

  k_conv_x<<<(kT * kH / 4) / 256, 256, 0, stream>>>(x, xb);
  k_conv_gateup<<<(kE * kIP * (kH / 4)) / 256, 256, 0, stream>>>(Wg, Wgb, kE);
  k_conv_gateup<<<(kE * kIP * (kH / 4)) / 256, 256, 0, stream>>>(Wu, Wub, kE);
  k_conv_gateup<<<(kIP * (kH / 4)) / 256, 256, 0, stream>>>(Sg, Sgb, 1);
  k_conv_gateup<<<(kIP * (kH / 4)) / 256, 256, 0, stream>>>(Su, Sub, 1);
  k_conv_down<<<(kE * kH * (kIP / 4)) / 256, 256, 0, stream>>>(Wd, Wdb, kE);
  k_conv_down<<<(kH * (kIP / 4)) / 256, 256, 0, stream>>>(Sd, Sdb, 1);

  k_gate<<<kT / 4, 256, 0, stream>>>(x, gw, tki, tkw, cnt);
  k_seg<<<1, 1, 0, stream>>>(cnt, seg, cur);
  k_fill<<<(kT * 3) / 256, 256, 0, stream>>>(tki, tkw, seg, cur, pt, pw, slt);

  dim3 gA(kIP / 128, kPairCap / 128);
  k_gu<<<gA, 256, 0, stream>>>(xb, Wgb, Wub, Sgb, Sub, pt, seg, hdn);
  dim3 gB(kH / 256, kPairCap / 128);
  k_down<<<gB, 256, 0, stream>>>(hdn, Wdb, Sdb, pw, seg, P);
  k_reduce<<<kT, 256, 0, stream>>>(P, slt, seg, out);
}

// Round 14
// 854.640 us; speedup vs baseline: 5.1818x; 5.1818x over previous
//
#include <hip/hip_runtime.h>
#include <hip/hip_bf16.h>
#include <cstdint>
#include <cstddef>

typedef __bf16 bf16x8 __attribute__((ext_vector_type(8)));
typedef float f32x4 __attribute__((ext_vector_type(4)));
typedef unsigned short u16x4 __attribute__((ext_vector_type(4)));
typedef unsigned short u16x8 __attribute__((ext_vector_type(8)));

namespace {
constexpr int kT = 8192;        // tokens
constexpr int kH = 1024;
constexpr int kE = 8;
constexpr int kI = 2752;
constexpr int kIP = 2816;       // I padded to 22*128
constexpr int kPairCap = 25728; // 201*128 >= 16384 + 8*127 + 8192

constexpr size_t SZ_XB  = (size_t)kT * kH * 2;
constexpr size_t SZ_WB  = (size_t)kE * kIP * kH * 2;
constexpr size_t SZ_SB  = (size_t)kIP * kH * 2;
constexpr size_t SZ_HDN = (size_t)kPairCap * kIP * 2;

constexpr size_t OFF_XB  = 0;
constexpr size_t OFF_WGB = OFF_XB + SZ_XB;
constexpr size_t OFF_WUB = OFF_WGB + SZ_WB;
constexpr size_t OFF_SGB = OFF_WUB + SZ_WB;
constexpr size_t OFF_SUB = OFF_SGB + SZ_SB;
constexpr size_t OFF_WDB = OFF_SUB + SZ_SB;           // = 120,586,240
constexpr size_t OFF_SDB = OFF_WDB + SZ_WB;
constexpr size_t OFF_HDN = OFF_SDB + SZ_SB;
constexpr size_t OFF_PT  = OFF_HDN + SZ_HDN;
constexpr size_t OFF_PW  = OFF_PT + (size_t)kPairCap * 4;
constexpr size_t OFF_SLT = OFF_PW + (size_t)kPairCap * 4;
constexpr size_t OFF_CNT = OFF_SLT + (size_t)kT * 2 * 4;
constexpr size_t OFF_CUR = OFF_CNT + 256;
constexpr size_t OFF_SEG = OFF_CUR + 256;
constexpr size_t WS_NEED = OFF_SEG + 256;
constexpr size_t OFF_P   = 0;   // P bf16 overlays dead X/Wg/Wu region
constexpr size_t OFF_TI  = OFF_HDN;
constexpr size_t OFF_TW  = OFF_HDN + (size_t)kT * 2 * 4;
static_assert((size_t)kPairCap * kH * 2 <= OFF_WDB, "P overlay fits");
}

__device__ __forceinline__ unsigned short f2bf(float f) {
  unsigned u = __builtin_bit_cast(unsigned, f);
  u += 0x7fffu + ((u >> 16) & 1u);
  return (unsigned short)(u >> 16);
}
__device__ __forceinline__ float bf2f(unsigned short v) {
  return __builtin_bit_cast(float, (unsigned)v << 16);
}

typedef __attribute__((address_space(1))) const unsigned int gu32;
typedef __attribute__((address_space(3))) unsigned int lu32;
__device__ __forceinline__ void gload16(const unsigned short* g, unsigned short* l) {
  __builtin_amdgcn_global_load_lds((gu32*)g, (lu32*)l, 16, 0, 0);
}

// ---------- fp32 -> bf16 converts (with I-padding) ----------
__global__ __launch_bounds__(256) void k_conv_x(const float* __restrict__ src,
                                                unsigned short* __restrict__ dst) {
  int i = blockIdx.x * 256 + threadIdx.x;
  f32x4 v = reinterpret_cast<const f32x4*>(src)[i];
  u16x4 o;
  #pragma unroll
  for (int j = 0; j < 4; ++j) o[j] = f2bf(v[j]);
  reinterpret_cast<u16x4*>(dst)[i] = o;
}

__global__ __launch_bounds__(256) void k_conv_gateup(const float* __restrict__ src,
                                                     unsigned short* __restrict__ dst,
                                                     int Eo) {
  int i = blockIdx.x * 256 + threadIdx.x;
  int c4 = i & 255;
  int r  = (i >> 8) % kIP;
  int e  = i / (256 * kIP);
  u16x4 o = (u16x4)0;
  if (r < kI) {
    f32x4 v = __builtin_nontemporal_load(
        reinterpret_cast<const f32x4*>(src) + ((size_t)e * kI + r) * 256 + c4);
    #pragma unroll
    for (int j = 0; j < 4; ++j) o[j] = f2bf(v[j]);
  }
  reinterpret_cast<u16x4*>(dst)[i] = o;
}

__global__ __launch_bounds__(256) void k_conv_down(const float* __restrict__ src,
                                                   unsigned short* __restrict__ dst,
                                                   int Eo) {
  int i = blockIdx.x * 256 + threadIdx.x;
  int c4 = i % 704;
  int rr = i / 704;
  int r  = rr % kH;
  int e  = rr / kH;
  u16x4 o = (u16x4)0;
  if (c4 < 688) {
    f32x4 v = __builtin_nontemporal_load(
        reinterpret_cast<const f32x4*>(src) + ((size_t)e * kH + r) * 688 + c4);
    #pragma unroll
    for (int j = 0; j < 4; ++j) o[j] = f2bf(v[j]);
  }
  reinterpret_cast<u16x4*>(dst)[i] = o;
}

// ---------- gate: softmax over 8 logits, top-2, renorm ----------
__global__ __launch_bounds__(256) void k_gate(const float* __restrict__ x,
                                              const float* __restrict__ gw,
                                              int* __restrict__ tki,
                                              float* __restrict__ tkw,
                                              int* __restrict__ cnt) {
  const int l = threadIdx.x & 63;
  const int t = blockIdx.x * 4 + (threadIdx.x >> 6);
  const float* xr = x + (size_t)t * kH + l * 16;
  float xv[16];
  #pragma unroll
  for (int j = 0; j < 16; j += 4) {
    f32x4 v = *reinterpret_cast<const f32x4*>(xr + j);
    xv[j] = v[0]; xv[j+1] = v[1]; xv[j+2] = v[2]; xv[j+3] = v[3];
  }
  float acc[kE];
  #pragma unroll
  for (int e = 0; e < kE; ++e) {
    const float* gr = gw + e * kH + l * 16;
    float s = 0.f;
    #pragma unroll
    for (int j = 0; j < 16; j += 4) {
      f32x4 g = *reinterpret_cast<const f32x4*>(gr + j);
      s += xv[j]*g[0] + xv[j+1]*g[1] + xv[j+2]*g[2] + xv[j+3]*g[3];
    }
    acc[e] = s;
  }
  #pragma unroll
  for (int e = 0; e < kE; ++e) {
    #pragma unroll
    for (int off = 32; off > 0; off >>= 1) acc[e] += __shfl_xor(acc[e], off, 64);
  }
  if (l == 0) {
    float m = acc[0];
    #pragma unroll
    for (int e = 1; e < kE; ++e) m = fmaxf(m, acc[e]);
    float p[kE]; float sum = 0.f;
    #pragma unroll
    for (int e = 0; e < kE; ++e) { p[e] = __expf(acc[e] - m); sum += p[e]; }
    float inv = 1.f / sum;
    int i1 = 0; float v1 = -1.f;
    #pragma unroll
    for (int e = 0; e < kE; ++e) { float s = p[e] * inv; if (s > v1) { v1 = s; i1 = e; } }
    int i2 = -1; float v2 = -1.f;
    #pragma unroll
    for (int e = 0; e < kE; ++e) {
      if (e == i1) continue;
      float s = p[e] * inv; if (s > v2) { v2 = s; i2 = e; }
    }
    float denom = v1 + v2 + 1e-20f;
    tki[t*2]   = i1; tki[t*2+1] = i2;
    tkw[t*2]   = v1 / denom; tkw[t*2+1] = v2 / denom;
    atomicAdd(&cnt[i1], 1); atomicAdd(&cnt[i2], 1);
  }
}

// ---------- segment offsets (padded to 128) ----------
__global__ void k_seg(const int* __restrict__ cnt, int* __restrict__ seg,
                      int* __restrict__ cur) {
  int off = 0;
  for (int e = 0; e < kE; ++e) {
    seg[e] = off; cur[e] = off;
    off += (cnt[e] + 127) & ~127;
  }
  seg[8] = off;
  seg[9] = off + kT;
}

// ---------- fill pair lists + slot map ----------
__global__ __launch_bounds__(256) void k_fill(const int* __restrict__ tki,
                                              const float* __restrict__ tkw,
                                              const int* __restrict__ seg,
                                              int* __restrict__ cur,
                                              int* __restrict__ pt,
                                              float* __restrict__ pw,
                                              int* __restrict__ slt) {
  int i = blockIdx.x * 256 + threadIdx.x;
  if (i < kT * 2) {
    int e = tki[i];
    int pos = atomicAdd(&cur[e], 1);
    pt[pos] = i >> 1;
    pw[pos] = tkw[i];
    slt[i] = pos;
  } else {
    int t = i - kT * 2;          // shared-expert segment, weight 1
    int pos = seg[8] + t;
    pt[pos] = t;
    pw[pos] = 1.0f;
  }
}

// ===================================================================
// Ring-2 counted-vmcnt pipeline, 24 KB slots (48 KB LDS). LDS permits
// 3 blocks/CU; __launch_bounds__(256,2) keeps the proven ~120-VGPR
// allocation (NO reg spill — round 13's (256,3) caused an 84-VGPR
// accumulator spill, 5.9 GB scratch writes, 5x regression).
// Loop: VMSYNC(6) -> COMP(slot) -> barrier -> STAGE into freed slot.
// ===================================================================

#define VMSYNC(N)                                                     \
  { asm volatile("s_waitcnt vmcnt(" #N ")" ::: "memory");             \
    __builtin_amdgcn_s_barrier();                                     \
    __builtin_amdgcn_sched_barrier(0); }

// ---------- pass A: hdn = silu(X Wg^T) * (X Wu^T) ----------
// Block 128 pairs x 128 I-cols dual, wave 64x64 dual.
// Slot 24KB: A[128x32]@0, G[128x32]@8192B, U[128x32]@16384B.
__global__ __launch_bounds__(256, 2) void k_gu(
    const unsigned short* __restrict__ xb,
    const unsigned short* __restrict__ Wgb,
    const unsigned short* __restrict__ Wub,
    const unsigned short* __restrict__ Sgb,
    const unsigned short* __restrict__ Sub,
    const int* __restrict__ pt,
    const int* __restrict__ seg,
    unsigned short* __restrict__ hdn) {
  __shared__ alignas(16) unsigned short lds[24576];  // 48 KB = 2 x 24KB slots
  const int tid = threadIdx.x;
  const int bn = blockIdx.x, bm = blockIdx.y;
  const int row0 = bm * 128, n0 = bn * 128;
  if (row0 >= seg[9]) return;
  int e = 0;
  while (e < 8 && row0 >= seg[e+1]) ++e;
  const unsigned short* Bg = (e < 8) ? Wgb + (size_t)e * kIP * kH : Sgb;
  const unsigned short* Bu = (e < 8) ? Wub + (size_t)e * kIP * kH : Sub;

  const int ur  = tid >> 2;
  const int csw = ((tid & 3) ^ ((tid >> 3) & 3)) * 8;   // swizzled elem offset
  const unsigned short* sA0 = xb + (size_t)pt[row0 + ur]      * kH + csw;
  const unsigned short* sA1 = xb + (size_t)pt[row0 + 64 + ur] * kH + csw;
  const unsigned short* sG0 = Bg + (size_t)(n0 + ur) * kH + csw;
  const unsigned short* sG1 = Bg + (size_t)(n0 + 64 + ur) * kH + csw;
  const unsigned short* sU0 = Bu + (size_t)(n0 + ur) * kH + csw;
  const unsigned short* sU1 = Bu + (size_t)(n0 + 64 + ur) * kH + csw;

  const int w = tid >> 6, l = tid & 63;
  const int wm = (w >> 1) * 64, wn = (w & 1) * 64;
  const int lr = l & 15, lk = l >> 4;
  unsigned short* const dst0 = &lds[w * 512];   // wave-uniform stage base

  int offA[4], offG[4];
  #pragma unroll
  for (int fm = 0; fm < 4; ++fm) {
    int r = wm + fm * 16 + lr;
    offA[fm] = (r * 4 + (lk ^ ((r >> 1) & 3))) * 16;
  }
  #pragma unroll
  for (int fn = 0; fn < 4; ++fn) {
    int rn = wn + fn * 16 + lr;
    offG[fn] = 8192 + (rn * 4 + (lk ^ ((rn >> 1) & 3))) * 16;
  }
  f32x4 ag[4][4] = {}, au[4][4] = {};

#define GU_STAGE(S)                                                   \
  { unsigned short* b = dst0 + (S) * 12288;                           \
    gload16(sA0, b);         gload16(sA1, b + 2048);                  \
    gload16(sG0, b + 4096);  gload16(sG1, b + 6144);                  \
    gload16(sU0, b + 8192);  gload16(sU1, b + 10240);                 \
    sA0 += 32; sA1 += 32; sG0 += 32; sG1 += 32; sU0 += 32; sU1 += 32; }

#define GU_COMP(S)                                                    \
  { const char* base = (const char*)lds + (S) * 24576;                \
    bf16x8 af[4], gf[4], uf[4];                                       \
    _Pragma("unroll")                                                 \
    for (int fm = 0; fm < 4; ++fm)                                    \
      af[fm] = *(const bf16x8*)(base + offA[fm]);                     \
    _Pragma("unroll")                                                 \
    for (int fn = 0; fn < 4; ++fn) {                                  \
      gf[fn] = *(const bf16x8*)(base + offG[fn]);                     \
      uf[fn] = *(const bf16x8*)(base + offG[fn] + 8192);              \
    }                                                                 \
    __builtin_amdgcn_s_setprio(1);                                    \
    _Pragma("unroll")                                                 \
    for (int fm = 0; fm < 4; ++fm) {                                  \
      _Pragma("unroll")                                               \
      for (int fn = 0; fn < 4; ++fn) {                                \
        ag[fm][fn] = __builtin_amdgcn_mfma_f32_16x16x32_bf16(af[fm], gf[fn], ag[fm][fn], 0, 0, 0); \
        au[fm][fn] = __builtin_amdgcn_mfma_f32_16x16x32_bf16(af[fm], uf[fn], au[fm][fn], 0, 0, 0); \
      }                                                               \
    }                                                                 \
    __builtin_amdgcn_s_setprio(0); }

  GU_STAGE(0); GU_STAGE(1);
  for (int h = 0; h < 30; ++h) {              // chunks 0..29; NH = 32
    VMSYNC(6);                                // chunk h landed; h+1 in flight
    GU_COMP(h & 1);
    __builtin_amdgcn_s_barrier();             // slot (h&1) fully consumed
    GU_STAGE(h & 1);                          // chunk h+2 into freed slot
  }
  VMSYNC(6); GU_COMP(0);                      // chunk 30
  __builtin_amdgcn_s_barrier();
  VMSYNC(0); GU_COMP(1);                      // chunk 31
#undef GU_STAGE
#undef GU_COMP

  #pragma unroll
  for (int fm = 0; fm < 4; ++fm) {
    #pragma unroll
    for (int fn = 0; fn < 4; ++fn) {
      #pragma unroll
      for (int j = 0; j < 4; ++j) {
        int r = wm + fm * 16 + lk * 4 + j;
        int c = wn + fn * 16 + lr;
        float g = ag[fm][fn][j], u = au[fm][fn][j];
        float h = g / (1.f + __expf(-g)) * u;
        hdn[(size_t)(row0 + r) * kIP + (n0 + c)] = f2bf(h);
      }
    }
  }
}

// ---------- pass B: P[pair,:] = pw[pair] * (hdn[pair,:] @ Wd^T) ----------
// Block 128x256, wave 64x128. Slot 24KB: A[128x32]@0, B[256x32]@8192B.
__global__ __launch_bounds__(256, 2) void k_down(
    const unsigned short* __restrict__ hdn,
    const unsigned short* __restrict__ Wdb,
    const unsigned short* __restrict__ Sdb,
    const float* __restrict__ pw,
    const int* __restrict__ seg,
    unsigned short* __restrict__ P) {
  __shared__ alignas(16) unsigned short lds[24576];  // 48 KB
  const int tid = threadIdx.x;
  const int bn = blockIdx.x, bm = blockIdx.y;
  const int row0 = bm * 128, n0 = bn * 256;
  if (row0 >= seg[9]) return;
  int e = 0;
  while (e < 8 && row0 >= seg[e+1]) ++e;
  const unsigned short* Bd = (e < 8) ? Wdb + (size_t)e * kH * kIP : Sdb;

  const int ur  = tid >> 2;
  const int csw = ((tid & 3) ^ ((tid >> 3) & 3)) * 8;
  const unsigned short* sA0 = hdn + (size_t)(row0 + ur)      * kIP + csw;
  const unsigned short* sA1 = hdn + (size_t)(row0 + 64 + ur) * kIP + csw;
  const unsigned short* sB0 = Bd  + (size_t)(n0 + ur)        * kIP + csw;
  const unsigned short* sB1 = Bd  + (size_t)(n0 + 64 + ur)   * kIP + csw;
  const unsigned short* sB2 = Bd  + (size_t)(n0 + 128 + ur)  * kIP + csw;
  const unsigned short* sB3 = Bd  + (size_t)(n0 + 192 + ur)  * kIP + csw;

  const int w = tid >> 6, l = tid & 63;
  const int wm = (w >> 1) * 64, wn = (w & 1) * 128;
  const int lr = l & 15, lk = l >> 4;
  unsigned short* const dst0 = &lds[w * 512];

  int offA[4], offB[8];
  #pragma unroll
  for (int fm = 0; fm < 4; ++fm) {
    int r = wm + fm * 16 + lr;
    offA[fm] = (r * 4 + (lk ^ ((r >> 1) & 3))) * 16;
  }
  #pragma unroll
  for (int fn = 0; fn < 8; ++fn) {
    int rn = wn + fn * 16 + lr;
    offB[fn] = 8192 + (rn * 4 + (lk ^ ((rn >> 1) & 3))) * 16;
  }
  f32x4 acc[4][8] = {};

#define DN_STAGE(S)                                                   \
  { unsigned short* b = dst0 + (S) * 12288;                           \
    gload16(sA0, b);         gload16(sA1, b + 2048);                  \
    gload16(sB0, b + 4096);  gload16(sB1, b + 6144);                  \
    gload16(sB2, b + 8192);  gload16(sB3, b + 10240);                 \
    sA0 += 32; sA1 += 32; sB0 += 32; sB1 += 32; sB2 += 32; sB3 += 32; }

#define DN_COMP(S)                                                    \
  { const char* base = (const char*)lds + (S) * 24576;                \
    bf16x8 af[4], bfr[8];                                             \
    _Pragma("unroll")                                                 \
    for (int fm = 0; fm < 4; ++fm)                                    \
      af[fm] = *(const bf16x8*)(base + offA[fm]);                     \
    _Pragma("unroll")                                                 \
    for (int fn = 0; fn < 8; ++fn)                                    \
      bfr[fn] = *(const bf16x8*)(base + offB[fn]);                    \
    __builtin_amdgcn_s_setprio(1);                                    \
    _Pragma("unroll")                                                 \
    for (int fm = 0; fm < 4; ++fm) {                                  \
      _Pragma("unroll")                                               \
      for (int fn = 0; fn < 8; ++fn)                                  \
        acc[fm][fn] = __builtin_amdgcn_mfma_f32_16x16x32_bf16(af[fm], bfr[fn], acc[fm][fn], 0, 0, 0); \
    }                                                                 \
    __builtin_amdgcn_s_setprio(0); }

  DN_STAGE(0); DN_STAGE(1);
  for (int h = 0; h < 86; ++h) {              // chunks 0..85; NH = 88
    VMSYNC(6);
    DN_COMP(h & 1);
    __builtin_amdgcn_s_barrier();
    DN_STAGE(h & 1);
  }
  VMSYNC(6); DN_COMP(0);                      // chunk 86
  __builtin_amdgcn_s_barrier();
  VMSYNC(0); DN_COMP(1);                      // chunk 87
#undef DN_STAGE
#undef DN_COMP

  #pragma unroll
  for (int fm = 0; fm < 4; ++fm) {
    #pragma unroll
    for (int j = 0; j < 4; ++j) {
      int r = row0 + wm + fm * 16 + lk * 4 + j;
      float wt = pw[r];
      unsigned short* prow = P + (size_t)r * kH + n0;
      #pragma unroll
      for (int fn = 0; fn < 8; ++fn)
        prow[wn + fn * 16 + lr] = f2bf(acc[fm][fn][j] * wt);
    }
  }
}

// ---------- final: y[t] = P[s1] + P[s2] + P[shared] (P in bf16) ----------
__global__ __launch_bounds__(256) void k_reduce(const unsigned short* __restrict__ P,
                                                const int* __restrict__ slt,
                                                const int* __restrict__ seg,
                                                float* __restrict__ out) {
  const int t = blockIdx.x, c = threadIdx.x;
  const int s1 = slt[t * 2], s2 = slt[t * 2 + 1], sh = seg[8] + t;
  u16x4 a = reinterpret_cast<const u16x4*>(P + (size_t)s1 * kH)[c];
  u16x4 b = reinterpret_cast<const u16x4*>(P + (size_t)s2 * kH)[c];
  u16x4 d = reinterpret_cast<const u16x4*>(P + (size_t)sh * kH)[c];
  f32x4 o;
  #pragma unroll
  for (int j = 0; j < 4; ++j) o[j] = bf2f(a[j]) + bf2f(b[j]) + bf2f(d[j]);
  reinterpret_cast<f32x4*>(out + (size_t)t * kH)[c] = o;
}

extern "C" void kernel_launch(void* const* d_in, const int* in_sizes, int n_in,
                              void* d_out, int out_size, void* d_ws, size_t ws_size,
                              hipStream_t stream) {
  const float* x  = (const float*)d_in[0];
  const float* gw = (const float*)d_in[1];
  const float* Wg = (const float*)d_in[2];
  const float* Wu = (const float*)d_in[3];
  const float* Wd = (const float*)d_in[4];
  const float* Sg = (const float*)d_in[5];
  const float* Su = (const float*)d_in[6];
  const float* Sd = (const float*)d_in[7];
  float* out = (float*)d_out;
  char* ws = (char*)d_ws;
  if (ws_size < WS_NEED) return;

  unsigned short* xb  = (unsigned short*)(ws + OFF_XB);
  unsigned short* Wgb = (unsigned short*)(ws + OFF_WGB);
  unsigned short* Wub = (unsigned short*)(ws + OFF_WUB);
  unsigned short* Sgb = (unsigned short*)(ws + OFF_SGB);
  unsigned short* Sub = (unsigned short*)(ws + OFF_SUB);
  unsigned short* Wdb = (unsigned short*)(ws + OFF_WDB);
  unsigned short* Sdb = (unsigned short*)(ws + OFF_SDB);
  unsigned short* hdn = (unsigned short*)(ws + OFF_HDN);
  unsigned short* P  = (unsigned short*)(ws + OFF_P);
  int*   pt  = (int*)(ws + OFF_PT);
  float* pw  = (float*)(ws + OFF_PW);
  int*   slt = (int*)(ws + OFF_SLT);
  int*   cnt = (int*)(ws + OFF_CNT);
  int*   cur = (int*)(ws + OFF_CUR);
  int*   seg = (int*)(ws + OFF_SEG);
  int*   tki = (int*)(ws + OFF_TI);
  float* tkw = (float*)(ws + OFF_TW);

  hipMemsetAsync(ws + OFF_PT, 0, OFF_SEG - OFF_PT, stream);

  k_conv_x<<<(kT * kH / 4) / 256, 256, 0, stream>>>(x, xb);
  k_conv_gateup<<<(kE * kIP * (kH / 4)) / 256, 256, 0, stream>>>(Wg, Wgb, kE);
  k_conv_gateup<<<(kE * kIP * (kH / 4)) / 256, 256, 0, stream>>>(Wu, Wub, kE);
  k_conv_gateup<<<(kIP * (kH / 4)) / 256, 256, 0, stream>>>(Sg, Sgb, 1);
  k_conv_gateup<<<(kIP * (kH / 4)) / 256, 256, 0, stream>>>(Su, Sub, 1);
  k_conv_down<<<(kE * kH * (kIP / 4)) / 256, 256, 0, stream>>>(Wd, Wdb, kE);
  k_conv_down<<<(kH * (kIP / 4)) / 256, 256, 0, stream>>>(Sd, Sdb, 1);

  k_gate<<<kT / 4, 256, 0, stream>>>(x, gw, tki, tkw, cnt);
  k_seg<<<1, 1, 0, stream>>>(cnt, seg, cur);
  k_fill<<<(kT * 3) / 256, 256, 0, stream>>>(tki, tkw, seg, cur, pt, pw, slt);

  dim3 gA(kIP / 128, kPairCap / 128);
  k_gu<<<gA, 256, 0, stream>>>(xb, Wgb, Wub, Sgb, Sub, pt, seg, hdn);
  dim3 gB(kH / 256, kPairCap / 128);
  k_down<<<gB, 256, 0, stream>>>(hdn, Wdb, Sdb, pw, seg, P);
  k_reduce<<<kT, 256, 0, stream>>>(P, slt, seg, out);
}

// Round 15
// 838.199 us; speedup vs baseline: 5.2834x; 1.0196x over previous
//
#include <hip/hip_runtime.h>
#include <hip/hip_bf16.h>
#include <cstdint>
#include <cstddef>

typedef __bf16 bf16x8 __attribute__((ext_vector_type(8)));
typedef float f32x4 __attribute__((ext_vector_type(4)));
typedef unsigned short u16x4 __attribute__((ext_vector_type(4)));
typedef unsigned short u16x8 __attribute__((ext_vector_type(8)));

namespace {
constexpr int kT = 8192;        // tokens
constexpr int kH = 1024;
constexpr int kE = 8;
constexpr int kI = 2752;
constexpr int kIP = 2816;       // I padded to 22*128
constexpr int kPairCap = 25728; // 201*128 >= 16384 + 8*127 + 8192

constexpr size_t SZ_XB  = (size_t)kT * kH * 2;
constexpr size_t SZ_WB  = (size_t)kE * kIP * kH * 2;
constexpr size_t SZ_SB  = (size_t)kIP * kH * 2;
constexpr size_t SZ_HDN = (size_t)kPairCap * kIP * 2;

constexpr size_t OFF_XB  = 0;
constexpr size_t OFF_WGB = OFF_XB + SZ_XB;
constexpr size_t OFF_WUB = OFF_WGB + SZ_WB;
constexpr size_t OFF_SGB = OFF_WUB + SZ_WB;
constexpr size_t OFF_SUB = OFF_SGB + SZ_SB;
constexpr size_t OFF_WDB = OFF_SUB + SZ_SB;           // = 120,586,240
constexpr size_t OFF_SDB = OFF_WDB + SZ_WB;
constexpr size_t OFF_HDN = OFF_SDB + SZ_SB;
constexpr size_t OFF_PT  = OFF_HDN + SZ_HDN;
constexpr size_t OFF_PW  = OFF_PT + (size_t)kPairCap * 4;
constexpr size_t OFF_SLT = OFF_PW + (size_t)kPairCap * 4;
constexpr size_t OFF_CNT = OFF_SLT + (size_t)kT * 2 * 4;
constexpr size_t OFF_CUR = OFF_CNT + 256;
constexpr size_t OFF_SEG = OFF_CUR + 256;
constexpr size_t WS_NEED = OFF_SEG + 256;
constexpr size_t OFF_P   = 0;   // P bf16 overlays dead X/Wg/Wu region
constexpr size_t OFF_TI  = OFF_HDN;
constexpr size_t OFF_TW  = OFF_HDN + (size_t)kT * 2 * 4;
static_assert((size_t)kPairCap * kH * 2 <= OFF_WDB, "P overlay fits");
}

__device__ __forceinline__ unsigned short f2bf(float f) {
  unsigned u = __builtin_bit_cast(unsigned, f);
  u += 0x7fffu + ((u >> 16) & 1u);
  return (unsigned short)(u >> 16);
}
__device__ __forceinline__ float bf2f(unsigned short v) {
  return __builtin_bit_cast(float, (unsigned)v << 16);
}

typedef __attribute__((address_space(1))) const unsigned int gu32;
typedef __attribute__((address_space(3))) unsigned int lu32;
__device__ __forceinline__ void gload16(const unsigned short* g, unsigned short* l) {
  __builtin_amdgcn_global_load_lds((gu32*)g, (lu32*)l, 16, 0, 0);
}

// ---------- fp32 -> bf16 weight converts (with I-padding) ----------
__global__ __launch_bounds__(256) void k_conv_gateup(const float* __restrict__ src,
                                                     unsigned short* __restrict__ dst,
                                                     int Eo) {
  int i = blockIdx.x * 256 + threadIdx.x;
  int c4 = i & 255;
  int r  = (i >> 8) % kIP;
  int e  = i / (256 * kIP);
  u16x4 o = (u16x4)0;
  if (r < kI) {
    f32x4 v = __builtin_nontemporal_load(
        reinterpret_cast<const f32x4*>(src) + ((size_t)e * kI + r) * 256 + c4);
    #pragma unroll
    for (int j = 0; j < 4; ++j) o[j] = f2bf(v[j]);
  }
  reinterpret_cast<u16x4*>(dst)[i] = o;
}

__global__ __launch_bounds__(256) void k_conv_down(const float* __restrict__ src,
                                                   unsigned short* __restrict__ dst,
                                                   int Eo) {
  int i = blockIdx.x * 256 + threadIdx.x;
  int c4 = i % 704;
  int rr = i / 704;
  int r  = rr % kH;
  int e  = rr / kH;
  u16x4 o = (u16x4)0;
  if (c4 < 688) {
    f32x4 v = __builtin_nontemporal_load(
        reinterpret_cast<const f32x4*>(src) + ((size_t)e * kH + r) * 688 + c4);
    #pragma unroll
    for (int j = 0; j < 4; ++j) o[j] = f2bf(v[j]);
  }
  reinterpret_cast<u16x4*>(dst)[i] = o;
}

// ---------- gate: softmax over 8 logits, top-2, renorm + x->bf16 ----------
// Fused: k_gate reads every element of x anyway, so it also emits xb
// (saves the separate k_conv_x pass: one 33.5 MB read + a launch).
__global__ __launch_bounds__(256) void k_gate(const float* __restrict__ x,
                                              const float* __restrict__ gw,
                                              unsigned short* __restrict__ xb,
                                              int* __restrict__ tki,
                                              float* __restrict__ tkw,
                                              int* __restrict__ cnt) {
  const int l = threadIdx.x & 63;
  const int t = blockIdx.x * 4 + (threadIdx.x >> 6);
  const float* xr = x + (size_t)t * kH + l * 16;
  float xv[16];
  #pragma unroll
  for (int j = 0; j < 16; j += 4) {
    f32x4 v = *reinterpret_cast<const f32x4*>(xr + j);
    xv[j] = v[0]; xv[j+1] = v[1]; xv[j+2] = v[2]; xv[j+3] = v[3];
  }
  // emit bf16 copy of this thread's 16 elements (covers all of x)
  {
    u16x8 o0, o1;
    #pragma unroll
    for (int j = 0; j < 8; ++j) { o0[j] = f2bf(xv[j]); o1[j] = f2bf(xv[8 + j]); }
    unsigned short* xo = xb + (size_t)t * kH + l * 16;
    *reinterpret_cast<u16x8*>(xo) = o0;
    *reinterpret_cast<u16x8*>(xo + 8) = o1;
  }
  float acc[kE];
  #pragma unroll
  for (int e = 0; e < kE; ++e) {
    const float* gr = gw + e * kH + l * 16;
    float s = 0.f;
    #pragma unroll
    for (int j = 0; j < 16; j += 4) {
      f32x4 g = *reinterpret_cast<const f32x4*>(gr + j);
      s += xv[j]*g[0] + xv[j+1]*g[1] + xv[j+2]*g[2] + xv[j+3]*g[3];
    }
    acc[e] = s;
  }
  #pragma unroll
  for (int e = 0; e < kE; ++e) {
    #pragma unroll
    for (int off = 32; off > 0; off >>= 1) acc[e] += __shfl_xor(acc[e], off, 64);
  }
  if (l == 0) {
    float m = acc[0];
    #pragma unroll
    for (int e = 1; e < kE; ++e) m = fmaxf(m, acc[e]);
    float p[kE]; float sum = 0.f;
    #pragma unroll
    for (int e = 0; e < kE; ++e) { p[e] = __expf(acc[e] - m); sum += p[e]; }
    float inv = 1.f / sum;
    int i1 = 0; float v1 = -1.f;
    #pragma unroll
    for (int e = 0; e < kE; ++e) { float s = p[e] * inv; if (s > v1) { v1 = s; i1 = e; } }
    int i2 = -1; float v2 = -1.f;
    #pragma unroll
    for (int e = 0; e < kE; ++e) {
      if (e == i1) continue;
      float s = p[e] * inv; if (s > v2) { v2 = s; i2 = e; }
    }
    float denom = v1 + v2 + 1e-20f;
    tki[t*2]   = i1; tki[t*2+1] = i2;
    tkw[t*2]   = v1 / denom; tkw[t*2+1] = v2 / denom;
    atomicAdd(&cnt[i1], 1); atomicAdd(&cnt[i2], 1);
  }
}

// ---------- segment offsets (padded to 128) ----------
__global__ void k_seg(const int* __restrict__ cnt, int* __restrict__ seg,
                      int* __restrict__ cur) {
  int off = 0;
  for (int e = 0; e < kE; ++e) {
    seg[e] = off; cur[e] = off;
    off += (cnt[e] + 127) & ~127;
  }
  seg[8] = off;
  seg[9] = off + kT;
}

// ---------- fill pair lists + slot map ----------
__global__ __launch_bounds__(256) void k_fill(const int* __restrict__ tki,
                                              const float* __restrict__ tkw,
                                              const int* __restrict__ seg,
                                              int* __restrict__ cur,
                                              int* __restrict__ pt,
                                              float* __restrict__ pw,
                                              int* __restrict__ slt) {
  int i = blockIdx.x * 256 + threadIdx.x;
  if (i < kT * 2) {
    int e = tki[i];
    int pos = atomicAdd(&cur[e], 1);
    pt[pos] = i >> 1;
    pw[pos] = tkw[i];
    slt[i] = pos;
  } else {
    int t = i - kT * 2;          // shared-expert segment, weight 1
    int pos = seg[8] + t;
    pt[pos] = t;
    pw[pos] = 1.0f;
  }
}

// ===================================================================
// Ring-3 counted-vmcnt pipeline, 24 KB slots (72 KB LDS, 2 blocks/CU).
// Grid: plain dim3, bn fastest (empirical FETCH minimum).
// Session-validated champion structure (round 12, 848 us).
// ===================================================================

#define VMSYNC(N)                                                     \
  { asm volatile("s_waitcnt vmcnt(" #N ")" ::: "memory");             \
    __builtin_amdgcn_s_barrier();                                     \
    __builtin_amdgcn_sched_barrier(0); }

// ---------- pass A: hdn = silu(X Wg^T) * (X Wu^T) ----------
// Block 128 pairs x 128 I-cols dual, wave 64x64 dual.
// Slot 24KB: A[128x32]@0, G[128x32]@8192B, U[128x32]@16384B.
__global__ __launch_bounds__(256, 2) void k_gu(
    const unsigned short* __restrict__ xb,
    const unsigned short* __restrict__ Wgb,
    const unsigned short* __restrict__ Wub,
    const unsigned short* __restrict__ Sgb,
    const unsigned short* __restrict__ Sub,
    const int* __restrict__ pt,
    const int* __restrict__ seg,
    unsigned short* __restrict__ hdn) {
  __shared__ alignas(16) unsigned short lds[36864];  // 72 KB = 3 x 24KB slots
  const int tid = threadIdx.x;
  const int bn = blockIdx.x, bm = blockIdx.y;
  const int row0 = bm * 128, n0 = bn * 128;
  if (row0 >= seg[9]) return;
  int e = 0;
  while (e < 8 && row0 >= seg[e+1]) ++e;
  const unsigned short* Bg = (e < 8) ? Wgb + (size_t)e * kIP * kH : Sgb;
  const unsigned short* Bu = (e < 8) ? Wub + (size_t)e * kIP * kH : Sub;

  const int ur  = tid >> 2;
  const int csw = ((tid & 3) ^ ((tid >> 3) & 3)) * 8;   // swizzled elem offset
  const unsigned short* sA0 = xb + (size_t)pt[row0 + ur]      * kH + csw;
  const unsigned short* sA1 = xb + (size_t)pt[row0 + 64 + ur] * kH + csw;
  const unsigned short* sG0 = Bg + (size_t)(n0 + ur) * kH + csw;
  const unsigned short* sG1 = Bg + (size_t)(n0 + 64 + ur) * kH + csw;
  const unsigned short* sU0 = Bu + (size_t)(n0 + ur) * kH + csw;
  const unsigned short* sU1 = Bu + (size_t)(n0 + 64 + ur) * kH + csw;

  const int w = tid >> 6, l = tid & 63;
  const int wm = (w >> 1) * 64, wn = (w & 1) * 64;
  const int lr = l & 15, lk = l >> 4;
  unsigned short* const dst0 = &lds[w * 512];   // wave-uniform stage base

  int offA[4], offG[4];
  #pragma unroll
  for (int fm = 0; fm < 4; ++fm) {
    int r = wm + fm * 16 + lr;
    offA[fm] = (r * 4 + (lk ^ ((r >> 1) & 3))) * 16;
  }
  #pragma unroll
  for (int fn = 0; fn < 4; ++fn) {
    int rn = wn + fn * 16 + lr;
    offG[fn] = 8192 + (rn * 4 + (lk ^ ((rn >> 1) & 3))) * 16;
  }
  f32x4 ag[4][4] = {}, au[4][4] = {};

#define GU_STAGE(S)                                                   \
  { unsigned short* b = dst0 + (S) * 12288;                           \
    gload16(sA0, b);         gload16(sA1, b + 2048);                  \
    gload16(sG0, b + 4096);  gload16(sG1, b + 6144);                  \
    gload16(sU0, b + 8192);  gload16(sU1, b + 10240);                 \
    sA0 += 32; sA1 += 32; sG0 += 32; sG1 += 32; sU0 += 32; sU1 += 32; }

#define GU_COMP(S)                                                    \
  { const char* base = (const char*)lds + (S) * 24576;                \
    bf16x8 af[4], gf[4], uf[4];                                       \
    _Pragma("unroll")                                                 \
    for (int fm = 0; fm < 4; ++fm)                                    \
      af[fm] = *(const bf16x8*)(base + offA[fm]);                     \
    _Pragma("unroll")                                                 \
    for (int fn = 0; fn < 4; ++fn) {                                  \
      gf[fn] = *(const bf16x8*)(base + offG[fn]);                     \
      uf[fn] = *(const bf16x8*)(base + offG[fn] + 8192);              \
    }                                                                 \
    __builtin_amdgcn_s_setprio(1);                                    \
    _Pragma("unroll")                                                 \
    for (int fm = 0; fm < 4; ++fm) {                                  \
      _Pragma("unroll")                                               \
      for (int fn = 0; fn < 4; ++fn) {                                \
        ag[fm][fn] = __builtin_amdgcn_mfma_f32_16x16x32_bf16(af[fm], gf[fn], ag[fm][fn], 0, 0, 0); \
        au[fm][fn] = __builtin_amdgcn_mfma_f32_16x16x32_bf16(af[fm], uf[fn], au[fm][fn], 0, 0, 0); \
      }                                                               \
    }                                                                 \
    __builtin_amdgcn_s_setprio(0); }

  GU_STAGE(0); GU_STAGE(1);
  int ss = 2, sc = 0;
  for (int h = 0; h < 30; ++h) {              // chunks 0..29; NH = 32
    GU_STAGE(ss); if (++ss == 3) ss = 0;
    VMSYNC(12);
    GU_COMP(sc); if (++sc == 3) sc = 0;
    __builtin_amdgcn_s_barrier();
  }
  VMSYNC(6); GU_COMP(sc); if (++sc == 3) sc = 0;
  __builtin_amdgcn_s_barrier();
  VMSYNC(0); GU_COMP(sc);
#undef GU_STAGE
#undef GU_COMP

  #pragma unroll
  for (int fm = 0; fm < 4; ++fm) {
    #pragma unroll
    for (int fn = 0; fn < 4; ++fn) {
      #pragma unroll
      for (int j = 0; j < 4; ++j) {
        int r = wm + fm * 16 + lk * 4 + j;
        int c = wn + fn * 16 + lr;
        float g = ag[fm][fn][j], u = au[fm][fn][j];
        float h = g / (1.f + __expf(-g)) * u;
        hdn[(size_t)(row0 + r) * kIP + (n0 + c)] = f2bf(h);
      }
    }
  }
}

// ---------- pass B: P[pair,:] = pw[pair] * (hdn[pair,:] @ Wd^T) ----------
// Block 128x256, wave 64x128. Slot 24KB: A[128x32]@0, B[256x32]@8192B.
__global__ __launch_bounds__(256, 2) void k_down(
    const unsigned short* __restrict__ hdn,
    const unsigned short* __restrict__ Wdb,
    const unsigned short* __restrict__ Sdb,
    const float* __restrict__ pw,
    const int* __restrict__ seg,
    unsigned short* __restrict__ P) {
  __shared__ alignas(16) unsigned short lds[36864];  // 72 KB
  const int tid = threadIdx.x;
  const int bn = blockIdx.x, bm = blockIdx.y;
  const int row0 = bm * 128, n0 = bn * 256;
  if (row0 >= seg[9]) return;
  int e = 0;
  while (e < 8 && row0 >= seg[e+1]) ++e;
  const unsigned short* Bd = (e < 8) ? Wdb + (size_t)e * kH * kIP : Sdb;

  const int ur  = tid >> 2;
  const int csw = ((tid & 3) ^ ((tid >> 3) & 3)) * 8;
  const unsigned short* sA0 = hdn + (size_t)(row0 + ur)      * kIP + csw;
  const unsigned short* sA1 = hdn + (size_t)(row0 + 64 + ur) * kIP + csw;
  const unsigned short* sB0 = Bd  + (size_t)(n0 + ur)        * kIP + csw;
  const unsigned short* sB1 = Bd  + (size_t)(n0 + 64 + ur)   * kIP + csw;
  const unsigned short* sB2 = Bd  + (size_t)(n0 + 128 + ur)  * kIP + csw;
  const unsigned short* sB3 = Bd  + (size_t)(n0 + 192 + ur)  * kIP + csw;

  const int w = tid >> 6, l = tid & 63;
  const int wm = (w >> 1) * 64, wn = (w & 1) * 128;
  const int lr = l & 15, lk = l >> 4;
  unsigned short* const dst0 = &lds[w * 512];

  int offA[4], offB[8];
  #pragma unroll
  for (int fm = 0; fm < 4; ++fm) {
    int r = wm + fm * 16 + lr;
    offA[fm] = (r * 4 + (lk ^ ((r >> 1) & 3))) * 16;
  }
  #pragma unroll
  for (int fn = 0; fn < 8; ++fn) {
    int rn = wn + fn * 16 + lr;
    offB[fn] = 8192 + (rn * 4 + (lk ^ ((rn >> 1) & 3))) * 16;
  }
  f32x4 acc[4][8] = {};

#define DN_STAGE(S)                                                   \
  { unsigned short* b = dst0 + (S) * 12288;                           \
    gload16(sA0, b);         gload16(sA1, b + 2048);                  \
    gload16(sB0, b + 4096);  gload16(sB1, b + 6144);                  \
    gload16(sB2, b + 8192);  gload16(sB3, b + 10240);                 \
    sA0 += 32; sA1 += 32; sB0 += 32; sB1 += 32; sB2 += 32; sB3 += 32; }

#define DN_COMP(S)                                                    \
  { const char* base = (const char*)lds + (S) * 24576;                \
    bf16x8 af[4], bfr[8];                                             \
    _Pragma("unroll")                                                 \
    for (int fm = 0; fm < 4; ++fm)                                    \
      af[fm] = *(const bf16x8*)(base + offA[fm]);                     \
    _Pragma("unroll")                                                 \
    for (int fn = 0; fn < 8; ++fn)                                    \
      bfr[fn] = *(const bf16x8*)(base + offB[fn]);                    \
    __builtin_amdgcn_s_setprio(1);                                    \
    _Pragma("unroll")                                                 \
    for (int fm = 0; fm < 4; ++fm) {                                  \
      _Pragma("unroll")                                               \
      for (int fn = 0; fn < 8; ++fn)                                  \
        acc[fm][fn] = __builtin_amdgcn_mfma_f32_16x16x32_bf16(af[fm], bfr[fn], acc[fm][fn], 0, 0, 0); \
    }                                                                 \
    __builtin_amdgcn_s_setprio(0); }

  DN_STAGE(0); DN_STAGE(1);
  int ss = 2, sc = 0;
  for (int h = 0; h < 86; ++h) {              // chunks 0..85; NH = 88
    DN_STAGE(ss); if (++ss == 3) ss = 0;
    VMSYNC(12);
    DN_COMP(sc); if (++sc == 3) sc = 0;
    __builtin_amdgcn_s_barrier();
  }
  VMSYNC(6); DN_COMP(sc); if (++sc == 3) sc = 0;
  __builtin_amdgcn_s_barrier();
  VMSYNC(0); DN_COMP(sc);
#undef DN_STAGE
#undef DN_COMP

  #pragma unroll
  for (int fm = 0; fm < 4; ++fm) {
    #pragma unroll
    for (int j = 0; j < 4; ++j) {
      int r = row0 + wm + fm * 16 + lk * 4 + j;
      float wt = pw[r];
      unsigned short* prow = P + (size_t)r * kH + n0;
      #pragma unroll
      for (int fn = 0; fn < 8; ++fn)
        prow[wn + fn * 16 + lr] = f2bf(acc[fm][fn][j] * wt);
    }
  }
}

// ---------- final: y[t] = P[s1] + P[s2] + P[shared] (P in bf16) ----------
__global__ __launch_bounds__(256) void k_reduce(const unsigned short* __restrict__ P,
                                                const int* __restrict__ slt,
                                                const int* __restrict__ seg,
                                                float* __restrict__ out) {
  const int t = blockIdx.x, c = threadIdx.x;
  const int s1 = slt[t * 2], s2 = slt[t * 2 + 1], sh = seg[8] + t;
  u16x4 a = reinterpret_cast<const u16x4*>(P + (size_t)s1 * kH)[c];
  u16x4 b = reinterpret_cast<const u16x4*>(P + (size_t)s2 * kH)[c];
  u16x4 d = reinterpret_cast<const u16x4*>(P + (size_t)sh * kH)[c];
  f32x4 o;
  #pragma unroll
  for (int j = 0; j < 4; ++j) o[j] = bf2f(a[j]) + bf2f(b[j]) + bf2f(d[j]);
  reinterpret_cast<f32x4*>(out + (size_t)t * kH)[c] = o;
}

extern "C" void kernel_launch(void* const* d_in, const int* in_sizes, int n_in,
                              void* d_out, int out_size, void* d_ws, size_t ws_size,
                              hipStream_t stream) {
  const float* x  = (const float*)d_in[0];
  const float* gw = (const float*)d_in[1];
  const float* Wg = (const float*)d_in[2];
  const float* Wu = (const float*)d_in[3];
  const float* Wd = (const float*)d_in[4];
  const float* Sg = (const float*)d_in[5];
  const float* Su = (const float*)d_in[6];
  const float* Sd = (const float*)d_in[7];
  float* out = (float*)d_out;
  char* ws = (char*)d_ws;
  if (ws_size < WS_NEED) return;

  unsigned short* xb  = (unsigned short*)(ws + OFF_XB);
  unsigned short* Wgb = (unsigned short*)(ws + OFF_WGB);
  unsigned short* Wub = (unsigned short*)(ws + OFF_WUB);
  unsigned short* Sgb = (unsigned short*)(ws + OFF_SGB);
  unsigned short* Sub = (unsigned short*)(ws + OFF_SUB);
  unsigned short* Wdb = (unsigned short*)(ws + OFF_WDB);
  unsigned short* Sdb = (unsigned short*)(ws + OFF_SDB);
  unsigned short* hdn = (unsigned short*)(ws + OFF_HDN);
  unsigned short* P  = (unsigned short*)(ws + OFF_P);
  int*   pt  = (int*)(ws + OFF_PT);
  float* pw  = (float*)(ws + OFF_PW);
  int*   slt = (int*)(ws + OFF_SLT);
  int*   cnt = (int*)(ws + OFF_CNT);
  int*   cur = (int*)(ws + OFF_CUR);
  int*   seg = (int*)(ws + OFF_SEG);
  int*   tki = (int*)(ws + OFF_TI);
  float* tkw = (float*)(ws + OFF_TW);

  hipMemsetAsync(ws + OFF_PT, 0, OFF_SEG - OFF_PT, stream);

  k_gate<<<kT / 4, 256, 0, stream>>>(x, gw, xb, tki, tkw, cnt);
  k_conv_gateup<<<(kE * kIP * (kH / 4)) / 256, 256, 0, stream>>>(Wg, Wgb, kE);
  k_conv_gateup<<<(kE * kIP * (kH / 4)) / 256, 256, 0, stream>>>(Wu, Wub, kE);
  k_conv_gateup<<<(kIP * (kH / 4)) / 256, 256, 0, stream>>>(Sg, Sgb, 1);
  k_conv_gateup<<<(kIP * (kH / 4)) / 256, 256, 0, stream>>>(Su, Sub, 1);
  k_conv_down<<<(kE * kH * (kIP / 4)) / 256, 256, 0, stream>>>(Wd, Wdb, kE);
  k_conv_down<<<(kH * (kIP / 4)) / 256, 256, 0, stream>>>(Sd, Sdb, 1);

  k_seg<<<1, 1, 0, stream>>>(cnt, seg, cur);
  k_fill<<<(kT * 3) / 256, 256, 0, stream>>>(tki, tkw, seg, cur, pt, pw, slt);

  dim3 gA(kIP / 128, kPairCap / 128);
  k_gu<<<gA, 256, 0, stream>>>(xb, Wgb, Wub, Sgb, Sub, pt, seg, hdn);
  dim3 gB(kH / 256, kPairCap / 128);
  k_down<<<gB, 256, 0, stream>>>(hdn, Wdb, Sdb, pw, seg, P);
  k_reduce<<<kT, 256, 0, stream>>>(P, slt, seg, out);
}